// Round 2
// 239.930 us; speedup vs baseline: 1.0931x; 1.0931x over previous
//
#include <hip/hip_runtime.h>
#include <hip/hip_bf16.h>
#include <math.h>

// Problem constants
#define D_MODEL 256
#define DEPTH 2
#define D_INNER 512
#define D_STATE 16
#define D_CONV 4
#define DT_RANK 16
#define BATCH 2
#define SEQLEN 2048
#define MROWS (BATCH * SEQLEN)   // 4096

#define LCH 8     // rows per chunk (halved: shorter serial scan, 2 blocks/CU)
#define NCH 512   // total chunks
#define CPB 256   // chunks per batch

typedef __attribute__((ext_vector_type(8))) short bf16x8;
typedef __attribute__((ext_vector_type(4))) float f32x4;

__device__ __forceinline__ float silu(float v) {
    return v / (1.0f + __expf(-v));
}

__device__ __forceinline__ ushort f2bf(float f) {
    union { float f; unsigned u; } v; v.f = f;
    unsigned r = v.u + 0x7FFFu + ((v.u >> 16) & 1u);
    return (ushort)(r >> 16);
}

__device__ __forceinline__ float bf2f(ushort u) {
    union { unsigned u; float f; } v; v.u = ((unsigned)u) << 16;
    return v.f;
}

__device__ __forceinline__ float softplus_f(float x) {
    // guarded log(1+exp): avoids the log1pf libcall; abs error ~1e-8 at tails
    return (x > 20.f) ? x : __logf(1.f + __expf(x));
}

#define XS_STR 260   // f32 stride, 11-row LN tile
#define HS_STR 264   // ushort stride, bf16 LN output (16 rows, 11 valid)
#define XC_STR 520   // ushort stride, xc/yy LDS tiles

// ---------------------------------------------------------------------------
// k_cvt: all three weight tensors f32 -> bf16 in one dispatch (grid 512x256).
// ---------------------------------------------------------------------------
__global__ __launch_bounds__(256) void k_cvt(
    const float* __restrict__ ipw, const float* __restrict__ xpw,
    const float* __restrict__ opw, ushort* __restrict__ ipwB,
    ushort* __restrict__ xpwB, ushort* __restrict__ opwB)
{
    size_t tid = (size_t)blockIdx.x * 256 + threadIdx.x;
    {
        float4 v = ((const float4*)ipw)[tid];
        ushort4 o = { f2bf(v.x), f2bf(v.y), f2bf(v.z), f2bf(v.w) };
        ((ushort4*)ipwB)[tid] = o;
    }
    if (tid < 12288) {
        float4 v = ((const float4*)xpw)[tid];
        ushort4 o = { f2bf(v.x), f2bf(v.y), f2bf(v.z), f2bf(v.w) };
        ((ushort4*)xpwB)[tid] = o;
    }
    if (tid < 65536) {
        float4 v = ((const float4*)opw)[tid];
        ushort4 o = { f2bf(v.x), f2bf(v.y), f2bf(v.z), f2bf(v.w) };
        ((ushort4*)opwB)[tid] = o;
    }
}

// ---------------------------------------------------------------------------
// k_front: 8-row chunk. LN (11 rows incl. 3-row conv halo) + in_proj MFMA +
// conv + SiLU + x_proj MFMA + scan_sum. Grid 512 x 512 -> 2 blocks/CU.
// MFMA tiles carry garbage rows (11 of 16 valid); outputs are row-guarded.
// ---------------------------------------------------------------------------
__global__ __launch_bounds__(512, 4) void k_front(
    const float* __restrict__ xin, const float* __restrict__ lnwL,
    const float* __restrict__ lnbL, const ushort* __restrict__ ipwL,
    const float* __restrict__ cwL, const float* __restrict__ cbL,
    const ushort* __restrict__ xpwL, const float* __restrict__ dpwL,
    const float* __restrict__ dpbL, const float* __restrict__ alogL,
    ushort* __restrict__ zsB, ushort* __restrict__ xcB,
    float* __restrict__ dbl, float* __restrict__ Ssum,
    float* __restrict__ sdsum)
{
    const int t = threadIdx.x, bid = blockIdx.x;
    const int lane = t & 63, w = t >> 6, l15 = lane & 15, quad = lane >> 4;
    __shared__ float  xs[11 * XS_STR];     // 11.4 KB
    __shared__ ushort hs[16 * HS_STR];     //  8.4 KB (rows 11-15 garbage)
    __shared__ ushort xi_s[11 * 512];      // 11.3 KB  rows: m0-3 .. m0+7
    __shared__ ushort xc_s[16 * XC_STR];   // 16.6 KB (rows 8-15 garbage)
    __shared__ float  dbl_s[8 * 52];       //  1.7 KB
    int m0 = bid * LCH;

    // ---- stage x rows m0-3 .. m0+7 (clamp row<0; batch masking via conv) --
    for (int i = t; i < 11 * 64; i += 512) {
        int r = i >> 6, c = (i & 63) * 4;
        int grow = m0 - 3 + r; if (grow < 0) grow = 0;
        float4 v = *(const float4*)(xin + (size_t)grow * D_MODEL + c);
        *(float4*)&xs[r * XS_STR + c] = v;
    }
    __syncthreads();

    // ---- LayerNorm, 11 rows x 16 threads ----
    if (t < 11 * 16) {
        int r = t >> 4, ci = t & 15;
        float s = 0.f, sq = 0.f;
        #pragma unroll
        for (int k = 0; k < 16; k++) {
            float v = xs[r * XS_STR + ci + 16 * k];
            s += v; sq += v * v;
        }
        #pragma unroll
        for (int off = 1; off < 16; off <<= 1) {
            s  += __shfl_xor(s, off, 16);
            sq += __shfl_xor(sq, off, 16);
        }
        float mu  = s * (1.0f / 256.f);
        float var = sq * (1.0f / 256.f) - mu * mu;
        float rst = rsqrtf(var + 1e-5f);
        #pragma unroll
        for (int k = 0; k < 16; k++) {
            int c = ci + 16 * k;
            float v = (xs[r * XS_STR + c] - mu) * rst * lnwL[c] + lnbL[c];
            hs[r * HS_STR + c] = f2bf(v);
        }
    }
    __syncthreads();

    // ---- in_proj MFMA: 8 waves x 8 tiles covering all 1024 n ----
    #pragma unroll
    for (int f = 0; f < 8; f++) {
        int n = w * 128 + f * 16 + l15;
        f32x4 acc = (f32x4){0.f, 0.f, 0.f, 0.f};
        for (int k0 = 0; k0 < D_MODEL; k0 += 32) {
            bf16x8 af = *(const bf16x8*)&hs[l15 * HS_STR + quad * 8 + k0];
            bf16x8 bw = *(const bf16x8*)(ipwL + (size_t)n * D_MODEL + quad * 8 + k0);
            acc = __builtin_amdgcn_mfma_f32_16x16x32_bf16(af, bw, acc, 0, 0, 0);
        }
        if (n < 512) {
            #pragma unroll
            for (int r2 = 0; r2 < 4; r2++) {
                int rl = quad * 4 + r2;
                if (rl < 11) xi_s[rl * 512 + n] = f2bf(acc[r2]);
            }
        } else {
            #pragma unroll
            for (int r2 = 0; r2 < 4; r2++) {
                int rl = quad * 4 + r2;
                if (rl >= 3 && rl < 11)
                    zsB[(size_t)(m0 + rl - 3) * D_INNER + (n - 512)] =
                        f2bf(silu(acc[r2]));
            }
        }
    }
    __syncthreads();

    // ---- conv(4) + SiLU -> xc_s + xcB. d = t, all 512 threads ----
    {
        float4 cw4 = *(const float4*)(cwL + t * 4);
        float cbv = cbL[t];
        #pragma unroll
        for (int rl = 0; rl < LCH; rl++) {
            int l = (m0 + rl) & (SEQLEN - 1);
            float s = cbv;
            if (l >= 3) s = fmaf(cw4.x, bf2f(xi_s[(rl + 0) * 512 + t]), s);
            if (l >= 2) s = fmaf(cw4.y, bf2f(xi_s[(rl + 1) * 512 + t]), s);
            if (l >= 1) s = fmaf(cw4.z, bf2f(xi_s[(rl + 2) * 512 + t]), s);
            s = fmaf(cw4.w, bf2f(xi_s[(rl + 3) * 512 + t]), s);
            ushort xcv = f2bf(silu(s));
            xc_s[rl * XC_STR + t] = xcv;
            xcB[(size_t)(m0 + rl) * D_INNER + t] = xcv;
        }
    }
    __syncthreads();

    // ---- x_proj MFMA (waves 0..2, one 16-n tile each; rows 8-15 garbage) --
    if (w < 3) {
        f32x4 acc = (f32x4){0.f, 0.f, 0.f, 0.f};
        for (int k0 = 0; k0 < D_INNER; k0 += 32) {
            bf16x8 af = *(const bf16x8*)&xc_s[l15 * XC_STR + quad * 8 + k0];
            bf16x8 bw = *(const bf16x8*)(xpwL + (size_t)(w * 16 + l15) * D_INNER + quad * 8 + k0);
            acc = __builtin_amdgcn_mfma_f32_16x16x32_bf16(af, bw, acc, 0, 0, 0);
        }
        int n = w * 16 + l15;
        #pragma unroll
        for (int r2 = 0; r2 < 4; r2++) {
            int rl = quad * 4 + r2;
            if (rl < LCH) {
                dbl_s[rl * 52 + n] = acc[r2];
                dbl[(size_t)(m0 + rl) * 48 + n] = acc[r2];
            }
        }
    }
    __syncthreads();

    // ---- scan_sum (d = t, all 512 threads), 8 serial steps ----
    {
        float a[16], wdp[16];
        #pragma unroll
        for (int n = 0; n < 16; n++) a[n] = -__expf(alogL[(size_t)t * 16 + n]);
        *(float4*)&wdp[0]  = *(const float4*)(dpwL + (size_t)t * 16 + 0);
        *(float4*)&wdp[4]  = *(const float4*)(dpwL + (size_t)t * 16 + 4);
        *(float4*)&wdp[8]  = *(const float4*)(dpwL + (size_t)t * 16 + 8);
        *(float4*)&wdp[12] = *(const float4*)(dpwL + (size_t)t * 16 + 12);
        float bias = dpbL[t];
        float h[16];
        #pragma unroll
        for (int n = 0; n < 16; n++) h[n] = 0.f;
        float sd = 0.f;
        for (int j = 0; j < LCH; j++) {
            const float* dp = &dbl_s[j * 52];
            float dot = bias;
            #pragma unroll
            for (int r2 = 0; r2 < 16; r2++) dot = fmaf(dp[r2], wdp[r2], dot);
            float dl = softplus_f(dot);
            float xv = bf2f(xc_s[j * XC_STR + t]);
            float u = dl * xv;
            sd += dl;
            #pragma unroll
            for (int n = 0; n < 16; n++)
                h[n] = fmaf(__expf(dl * a[n]), h[n], dp[16 + n] * u);
        }
        size_t sbase = (size_t)bid * 16 * D_INNER + t;
        #pragma unroll
        for (int n = 0; n < 16; n++) Ssum[sbase + (size_t)n * D_INNER] = h[n];
        sdsum[(size_t)bid * D_INNER + t] = sd;
    }
}

// ---------------------------------------------------------------------------
// k_comb: two-level exclusive prefix over 512 chunk summaries.
// Chains = (b,n,d) = 16384; 16 segments x 16 chunks per chain.
// Grid 512 x 512: block = 32 chains (consecutive d, same b,n) x 16 segments.
// Phase1: per-segment summary (chunk values cached in regs).
// Phase2: 16-step segment scan per chain in LDS.
// Phase3: register replay, write exclusive prefixes. Ssum read once/write once.
// ---------------------------------------------------------------------------
__global__ __launch_bounds__(512, 4) void k_comb(
    const float* __restrict__ alogL, const float* __restrict__ sdsum,
    float* __restrict__ Ssum)
{
    const int t = threadIdx.x, bid = blockIdx.x;
    __shared__ float S_l[32][17], sd_l[32][17];
    int ch32 = t & 31, seg = t >> 5;
    int chain = bid * 32 + ch32;
    int d = chain & 511;
    int n = (chain >> 9) & 15;
    int b = chain >> 13;
    float a = -__expf(alogL[(size_t)d * 16 + n]);
    int c0 = b * CPB + seg * 16;

    float s_r[16], sd_r[16];
    float S = 0.f, sdt = 0.f;
    #pragma unroll
    for (int j = 0; j < 16; j++) {
        size_t c = (size_t)(c0 + j);
        float s  = Ssum[(c * 16 + n) * D_INNER + d];
        float sd = sdsum[c * D_INNER + d];
        s_r[j] = s; sd_r[j] = sd;
        S = fmaf(__expf(a * sd), S, s);
        sdt += sd;
    }
    S_l[ch32][seg] = S;
    sd_l[ch32][seg] = sdt;
    __syncthreads();

    if (t < 32) {
        float hi = 0.f;
        #pragma unroll
        for (int g = 0; g < 16; g++) {
            float Sv = S_l[t][g], sdv = sd_l[t][g];
            S_l[t][g] = hi;
            hi = fmaf(__expf(a * sdv), hi, Sv);
        }
    }
    __syncthreads();

    float hi = S_l[ch32][seg];
    #pragma unroll
    for (int j = 0; j < 16; j++) {
        size_t c = (size_t)(c0 + j);
        Ssum[(c * 16 + n) * D_INNER + d] = hi;
        hi = fmaf(__expf(a * sd_r[j]), hi, s_r[j]);
    }
}

// ---------------------------------------------------------------------------
// k_back: 8-row chunk. Rescan from true h_init + D-skip + SiLU(z) gate,
// yy in LDS (rows 8-15 garbage), out_proj MFMA + residual. Grid 512 x 512.
// ---------------------------------------------------------------------------
__global__ __launch_bounds__(512) void k_back(
    const float* __restrict__ dbl, const ushort* __restrict__ xcB,
    const ushort* __restrict__ zsB, const float* __restrict__ Ssum,
    const float* __restrict__ dpwL, const float* __restrict__ dpbL,
    const float* __restrict__ alogL, const float* __restrict__ dparL,
    const ushort* __restrict__ opwL, const float* __restrict__ xin,
    float* __restrict__ xout)
{
    const int t = threadIdx.x, bid = blockIdx.x;
    const int lane = t & 63, w = t >> 6, l15 = lane & 15, quad = lane >> 4;
    __shared__ ushort yy_s[16 * XC_STR];   // 16.6 KB (rows 8-15 garbage)
    int m0 = bid * LCH;

    // ---- rescan, d = t ----
    {
        float a[16], wdp[16];
        #pragma unroll
        for (int n = 0; n < 16; n++) a[n] = -__expf(alogL[(size_t)t * 16 + n]);
        *(float4*)&wdp[0]  = *(const float4*)(dpwL + (size_t)t * 16 + 0);
        *(float4*)&wdp[4]  = *(const float4*)(dpwL + (size_t)t * 16 + 4);
        *(float4*)&wdp[8]  = *(const float4*)(dpwL + (size_t)t * 16 + 8);
        *(float4*)&wdp[12] = *(const float4*)(dpwL + (size_t)t * 16 + 12);
        float bias = dpbL[t];
        float Dd = dparL[t];
        float h[16];
        size_t sbase = (size_t)bid * 16 * D_INNER + t;
        #pragma unroll
        for (int n = 0; n < 16; n++) h[n] = Ssum[sbase + (size_t)n * D_INNER];
        for (int j = 0; j < LCH; j++) {
            int row = m0 + j;
            const float* dp = dbl + (size_t)row * 48;
            float dot = bias;
            #pragma unroll
            for (int q = 0; q < 4; q++) {
                float4 dv = *(const float4*)(dp + q * 4);
                dot = fmaf(dv.x, wdp[4 * q + 0], dot);
                dot = fmaf(dv.y, wdp[4 * q + 1], dot);
                dot = fmaf(dv.z, wdp[4 * q + 2], dot);
                dot = fmaf(dv.w, wdp[4 * q + 3], dot);
            }
            float dl = softplus_f(dot);
            float xv = bf2f(xcB[(size_t)row * D_INNER + t]);
            float gate = bf2f(zsB[(size_t)row * D_INNER + t]);
            float u = dl * xv;
            float y0 = 0.f, y1 = 0.f, y2 = 0.f, y3 = 0.f;
            #pragma unroll
            for (int q = 0; q < 4; q++) {
                float4 Bv = *(const float4*)(dp + 16 + q * 4);
                float4 Cv = *(const float4*)(dp + 32 + q * 4);
                h[4 * q + 0] = fmaf(__expf(dl * a[4 * q + 0]), h[4 * q + 0], Bv.x * u);
                h[4 * q + 1] = fmaf(__expf(dl * a[4 * q + 1]), h[4 * q + 1], Bv.y * u);
                h[4 * q + 2] = fmaf(__expf(dl * a[4 * q + 2]), h[4 * q + 2], Bv.z * u);
                h[4 * q + 3] = fmaf(__expf(dl * a[4 * q + 3]), h[4 * q + 3], Bv.w * u);
                y0 = fmaf(h[4 * q + 0], Cv.x, y0);
                y1 = fmaf(h[4 * q + 1], Cv.y, y1);
                y2 = fmaf(h[4 * q + 2], Cv.z, y2);
                y3 = fmaf(h[4 * q + 3], Cv.w, y3);
            }
            float y = (y0 + y1) + (y2 + y3) + xv * Dd;
            yy_s[j * XC_STR + t] = f2bf(y * gate);
        }
    }
    __syncthreads();

    // ---- out_proj MFMA + residual: 8 waves x 2 n-tiles (rows 0..7 valid) --
    #pragma unroll
    for (int f = 0; f < 2; f++) {
        int n = w * 32 + f * 16 + l15;
        f32x4 acc = (f32x4){0.f, 0.f, 0.f, 0.f};
        for (int k0 = 0; k0 < D_INNER; k0 += 32) {
            bf16x8 af = *(const bf16x8*)&yy_s[l15 * XC_STR + quad * 8 + k0];
            bf16x8 bw = *(const bf16x8*)(opwL + (size_t)n * D_INNER + quad * 8 + k0);
            acc = __builtin_amdgcn_mfma_f32_16x16x32_bf16(af, bw, acc, 0, 0, 0);
        }
        #pragma unroll
        for (int r2 = 0; r2 < 4; r2++) {
            int rl = quad * 4 + r2;
            if (rl < LCH) {
                int row = m0 + rl;
                xout[(size_t)row * D_MODEL + n] =
                    acc[r2] + xin[(size_t)row * D_MODEL + n];
            }
        }
    }
}

// ---------------------------------------------------------------------------
// Launch. Inter-layer activation routed through d_out (no xbuf): layer-1
// k_back reads/writes the same element from the same thread, and k_front of
// layer 1 is a separate dispatch after k_back of layer 0 -> safe.
// ---------------------------------------------------------------------------
extern "C" void kernel_launch(void* const* d_in, const int* in_sizes, int n_in,
                              void* d_out, int out_size, void* d_ws, size_t ws_size,
                              hipStream_t stream)
{
    const float* x    = (const float*)d_in[0];
    const float* lnw  = (const float*)d_in[1];
    const float* lnb  = (const float*)d_in[2];
    const float* ipw  = (const float*)d_in[3];
    const float* cw   = (const float*)d_in[4];
    const float* cb   = (const float*)d_in[5];
    const float* xpw  = (const float*)d_in[6];
    const float* dpw  = (const float*)d_in[7];
    const float* dpb  = (const float*)d_in[8];
    const float* alog = (const float*)d_in[9];
    const float* dpar = (const float*)d_in[10];
    const float* opw  = (const float*)d_in[11];
    float* out = (float*)d_out;

    char* p = (char*)d_ws;
    auto alloc = [&](size_t bytes) { char* r = p; p += (bytes + 255) & ~(size_t)255; return r; };
    ushort* zsB   = (ushort*)alloc((size_t)MROWS * D_INNER * 2);
    ushort* xcB   = (ushort*)alloc((size_t)MROWS * D_INNER * 2);
    float*  dbl   = (float*)alloc((size_t)MROWS * 48 * 4);
    float*  Ssum  = (float*)alloc((size_t)NCH * 16 * D_INNER * 4);
    float*  sdsum = (float*)alloc((size_t)NCH * D_INNER * 4);
    ushort* ipwB  = (ushort*)alloc((size_t)DEPTH * 2 * D_INNER * D_MODEL * 2);
    ushort* xpwB  = (ushort*)alloc((size_t)DEPTH * 48 * D_INNER * 2);
    ushort* opwB  = (ushort*)alloc((size_t)DEPTH * D_MODEL * D_INNER * 2);

    k_cvt<<<512, 256, 0, stream>>>(ipw, xpw, opw, ipwB, xpwB, opwB);

    for (int lyr = 0; lyr < DEPTH; lyr++) {
        const float* xin = (lyr == 0) ? x : out;
        float* xout = out;
        const float* alogL = alog + (size_t)lyr * D_INNER * D_STATE;
        const float* dpwL  = dpw + (size_t)lyr * D_INNER * DT_RANK;
        const float* dpbL  = dpb + lyr * D_INNER;

        k_front<<<NCH, 512, 0, stream>>>(
            xin, lnw + lyr * D_MODEL, lnb + lyr * D_MODEL,
            ipwB + (size_t)lyr * 2 * D_INNER * D_MODEL,
            cw + (size_t)lyr * D_INNER * D_CONV, cb + lyr * D_INNER,
            xpwB + (size_t)lyr * 48 * D_INNER, dpwL, dpbL, alogL,
            zsB, xcB, dbl, Ssum, sdsum);

        k_comb<<<512, 512, 0, stream>>>(alogL, sdsum, Ssum);

        k_back<<<NCH, 512, 0, stream>>>(
            dbl, xcB, zsB, Ssum, dpwL, dpbL, alogL,
            dpar + lyr * D_INNER,
            opwB + (size_t)lyr * D_MODEL * D_INNER, xin, xout);
    }
}

// Round 3
// 207.572 us; speedup vs baseline: 1.2635x; 1.1559x over previous
//
#include <hip/hip_runtime.h>
#include <hip/hip_bf16.h>
#include <math.h>

// Problem constants
#define D_MODEL 256
#define DEPTH 2
#define D_INNER 512
#define D_STATE 16
#define D_CONV 4
#define DT_RANK 16
#define BATCH 2
#define SEQLEN 2048
#define MROWS (BATCH * SEQLEN)   // 4096

#define LCH 8     // rows per chunk
#define NCH 512   // total chunks
#define CPB 256   // chunks per batch

typedef __attribute__((ext_vector_type(8))) short bf16x8;
typedef __attribute__((ext_vector_type(4))) float f32x4;

__device__ __forceinline__ float silu(float v) {
    return v / (1.0f + __expf(-v));
}

__device__ __forceinline__ ushort f2bf(float f) {
    union { float f; unsigned u; } v; v.f = f;
    unsigned r = v.u + 0x7FFFu + ((v.u >> 16) & 1u);
    return (ushort)(r >> 16);
}

__device__ __forceinline__ float bf2f(ushort u) {
    union { unsigned u; float f; } v; v.u = ((unsigned)u) << 16;
    return v.f;
}

__device__ __forceinline__ float softplus_f(float x) {
    return (x > 20.f) ? x : __logf(1.f + __expf(x));
}

#define XS_STR 260   // f32 stride, 11-row LN tile
#define HS_STR 264   // ushort stride, bf16 LN output (16 rows, 11 valid)
#define XC_STR 520   // ushort stride, xc/yy LDS tiles

// ---------------------------------------------------------------------------
// k_cvt: f32 -> bf16 AND re-layout to MFMA tile-major: per (nt,kt) a 1-KB
// tile [16 r][32 c] so one wave weight-load = one coalesced 1-KB segment.
// Grid 512x256 = 131072 threads; each converts 4 consecutive k of one n.
// ---------------------------------------------------------------------------
__global__ __launch_bounds__(256) void k_cvt(
    const float* __restrict__ ipw, const float* __restrict__ xpw,
    const float* __restrict__ opw, ushort* __restrict__ ipwT,
    ushort* __restrict__ xpwT, ushort* __restrict__ opwT)
{
    size_t tid = (size_t)blockIdx.x * 256 + threadIdx.x;
    {   // ipw: [2][1024 n][256 k] -> per layer [64 nt][8 kt][16 r][32 c]
        int lyr = (int)(tid >> 16), rem = (int)(tid & 65535);
        int n = rem >> 6, k = (rem & 63) * 4;
        float4 v = *(const float4*)(ipw + ((size_t)lyr * 1024 + n) * 256 + k);
        int nt = n >> 4, r = n & 15, kt = k >> 5, c = k & 31;
        ushort4 o = { f2bf(v.x), f2bf(v.y), f2bf(v.z), f2bf(v.w) };
        *(ushort4*)(ipwT + (size_t)lyr * 262144 + (nt * 8 + kt) * 512 + r * 32 + c) = o;
    }
    if (tid < 12288) {   // xpw: [2][48][512] -> per layer [3 nt][16 kt] tiles
        int lyr = (int)(tid / 6144), rem = (int)(tid % 6144);
        int n = rem >> 7, k = (rem & 127) * 4;
        float4 v = *(const float4*)(xpw + ((size_t)lyr * 48 + n) * 512 + k);
        int nt = n >> 4, r = n & 15, kt = k >> 5, c = k & 31;
        ushort4 o = { f2bf(v.x), f2bf(v.y), f2bf(v.z), f2bf(v.w) };
        *(ushort4*)(xpwT + (size_t)lyr * 24576 + (nt * 16 + kt) * 512 + r * 32 + c) = o;
    }
    if (tid < 65536) {   // opw: [2][256][512] -> per layer [16 nt][16 kt]
        int lyr = (int)(tid >> 15), rem = (int)(tid & 32767);
        int n = rem >> 7, k = (rem & 127) * 4;
        float4 v = *(const float4*)(opw + ((size_t)lyr * 256 + n) * 512 + k);
        int nt = n >> 4, r = n & 15, kt = k >> 5, c = k & 31;
        ushort4 o = { f2bf(v.x), f2bf(v.y), f2bf(v.z), f2bf(v.w) };
        *(ushort4*)(opwT + (size_t)lyr * 131072 + (nt * 16 + kt) * 512 + r * 32 + c) = o;
    }
}

// ---------------------------------------------------------------------------
// k_front: 8-row chunk. LN (11 rows incl. conv halo) + in_proj MFMA (tiled
// weights, k-outer/f-inner, hoisted A-frags) + conv + x_proj + scan_sum.
// Grid 512 x 512.
// ---------------------------------------------------------------------------
__global__ __launch_bounds__(512, 3) void k_front(
    const float* __restrict__ xin, const float* __restrict__ lnwL,
    const float* __restrict__ lnbL, const ushort* __restrict__ ipwT,
    const float* __restrict__ cwL, const float* __restrict__ cbL,
    const ushort* __restrict__ xpwT, const float* __restrict__ dpwL,
    const float* __restrict__ dpbL, const float* __restrict__ alogL,
    ushort* __restrict__ zsB, ushort* __restrict__ xcB,
    float* __restrict__ dbl, float* __restrict__ Ssum,
    float* __restrict__ sdsum)
{
    const int t = threadIdx.x, bid = blockIdx.x;
    const int lane = t & 63, w = t >> 6, l15 = lane & 15, quad = lane >> 4;
    __shared__ float  xs[11 * XS_STR];     // 11.4 KB
    __shared__ ushort hs[16 * HS_STR];     //  8.4 KB (rows 11-15 garbage)
    __shared__ ushort xi_s[11 * 512];      // 11.3 KB  rows: m0-3 .. m0+7
    __shared__ ushort xc_s[16 * XC_STR];   // 16.6 KB (rows 8-15 garbage)
    __shared__ float  dbl_s[8 * 52];       //  1.7 KB
    int m0 = bid * LCH;

    // ---- stage x rows m0-3 .. m0+7 (clamp row<0) ----
    for (int i = t; i < 11 * 64; i += 512) {
        int r = i >> 6, c = (i & 63) * 4;
        int grow = m0 - 3 + r; if (grow < 0) grow = 0;
        float4 v = *(const float4*)(xin + (size_t)grow * D_MODEL + c);
        *(float4*)&xs[r * XS_STR + c] = v;
    }
    __syncthreads();

    // ---- LayerNorm, 11 rows x 16 threads ----
    if (t < 11 * 16) {
        int r = t >> 4, ci = t & 15;
        float s = 0.f, sq = 0.f;
        #pragma unroll
        for (int k = 0; k < 16; k++) {
            float v = xs[r * XS_STR + ci + 16 * k];
            s += v; sq += v * v;
        }
        #pragma unroll
        for (int off = 1; off < 16; off <<= 1) {
            s  += __shfl_xor(s, off, 16);
            sq += __shfl_xor(sq, off, 16);
        }
        float mu  = s * (1.0f / 256.f);
        float var = sq * (1.0f / 256.f) - mu * mu;
        float rst = rsqrtf(var + 1e-5f);
        #pragma unroll
        for (int k = 0; k < 16; k++) {
            int c = ci + 16 * k;
            float v = (xs[r * XS_STR + c] - mu) * rst * lnwL[c] + lnbL[c];
            hs[r * HS_STR + c] = f2bf(v);
        }
    }
    __syncthreads();

    // ---- in_proj MFMA: hoisted af, k-outer / f-inner, tiled weights ----
    {
        bf16x8 af[8];
        #pragma unroll
        for (int k8 = 0; k8 < 8; k8++)
            af[k8] = *(const bf16x8*)&hs[l15 * HS_STR + quad * 8 + k8 * 32];
        f32x4 acc[8];
        #pragma unroll
        for (int f = 0; f < 8; f++) acc[f] = (f32x4){0.f, 0.f, 0.f, 0.f};
        const ushort* wb = ipwT + (size_t)w * 64 * 512 + l15 * 32 + quad * 8;
        #pragma unroll
        for (int k8 = 0; k8 < 8; k8++) {
            #pragma unroll
            for (int f = 0; f < 8; f++) {
                bf16x8 bw = *(const bf16x8*)(wb + (f * 8 + k8) * 512);
                acc[f] = __builtin_amdgcn_mfma_f32_16x16x32_bf16(af[k8], bw, acc[f], 0, 0, 0);
            }
        }
        #pragma unroll
        for (int f = 0; f < 8; f++) {
            int n = w * 128 + f * 16 + l15;
            if (n < 512) {
                #pragma unroll
                for (int r2 = 0; r2 < 4; r2++) {
                    int rl = quad * 4 + r2;
                    if (rl < 11) xi_s[rl * 512 + n] = f2bf(acc[f][r2]);
                }
            } else {
                #pragma unroll
                for (int r2 = 0; r2 < 4; r2++) {
                    int rl = quad * 4 + r2;
                    if (rl >= 3 && rl < 11)
                        zsB[(size_t)(m0 + rl - 3) * D_INNER + (n - 512)] =
                            f2bf(silu(acc[f][r2]));
                }
            }
        }
    }
    __syncthreads();

    // ---- conv(4) + SiLU -> xc_s + xcB. d = t, all 512 threads ----
    {
        float4 cw4 = *(const float4*)(cwL + t * 4);
        float cbv = cbL[t];
        #pragma unroll
        for (int rl = 0; rl < LCH; rl++) {
            int l = (m0 + rl) & (SEQLEN - 1);
            float s = cbv;
            if (l >= 3) s = fmaf(cw4.x, bf2f(xi_s[(rl + 0) * 512 + t]), s);
            if (l >= 2) s = fmaf(cw4.y, bf2f(xi_s[(rl + 1) * 512 + t]), s);
            if (l >= 1) s = fmaf(cw4.z, bf2f(xi_s[(rl + 2) * 512 + t]), s);
            s = fmaf(cw4.w, bf2f(xi_s[(rl + 3) * 512 + t]), s);
            ushort xcv = f2bf(silu(s));
            xc_s[rl * XC_STR + t] = xcv;
            xcB[(size_t)(m0 + rl) * D_INNER + t] = xcv;
        }
    }
    __syncthreads();

    // ---- x_proj MFMA (waves 0..2): prefetch all 16 bw, then MFMA chain ----
    if (w < 3) {
        const ushort* wb = xpwT + (size_t)w * 16 * 512 + l15 * 32 + quad * 8;
        bf16x8 bw[16];
        #pragma unroll
        for (int k8 = 0; k8 < 16; k8++)
            bw[k8] = *(const bf16x8*)(wb + k8 * 512);
        f32x4 acc = (f32x4){0.f, 0.f, 0.f, 0.f};
        #pragma unroll
        for (int k8 = 0; k8 < 16; k8++) {
            bf16x8 af = *(const bf16x8*)&xc_s[l15 * XC_STR + quad * 8 + k8 * 32];
            acc = __builtin_amdgcn_mfma_f32_16x16x32_bf16(af, bw[k8], acc, 0, 0, 0);
        }
        int n = w * 16 + l15;
        #pragma unroll
        for (int r2 = 0; r2 < 4; r2++) {
            int rl = quad * 4 + r2;
            if (rl < LCH) {
                dbl_s[rl * 52 + n] = acc[r2];
                dbl[(size_t)(m0 + rl) * 48 + n] = acc[r2];
            }
        }
    }
    __syncthreads();

    // ---- scan_sum (d = t, all 512 threads), 8 serial steps ----
    {
        float a[16], wdp[16];
        #pragma unroll
        for (int n = 0; n < 16; n++) a[n] = -__expf(alogL[(size_t)t * 16 + n]);
        *(float4*)&wdp[0]  = *(const float4*)(dpwL + (size_t)t * 16 + 0);
        *(float4*)&wdp[4]  = *(const float4*)(dpwL + (size_t)t * 16 + 4);
        *(float4*)&wdp[8]  = *(const float4*)(dpwL + (size_t)t * 16 + 8);
        *(float4*)&wdp[12] = *(const float4*)(dpwL + (size_t)t * 16 + 12);
        float bias = dpbL[t];
        float h[16];
        #pragma unroll
        for (int n = 0; n < 16; n++) h[n] = 0.f;
        float sd = 0.f;
        for (int j = 0; j < LCH; j++) {
            const float* dp = &dbl_s[j * 52];
            float d0 = 0.f, d1 = 0.f;
            #pragma unroll
            for (int r2 = 0; r2 < 8; r2++) {
                d0 = fmaf(dp[r2], wdp[r2], d0);
                d1 = fmaf(dp[8 + r2], wdp[8 + r2], d1);
            }
            float dl = softplus_f(bias + d0 + d1);
            float xv = bf2f(xc_s[j * XC_STR + t]);
            float u = dl * xv;
            sd += dl;
            #pragma unroll
            for (int n = 0; n < 16; n++)
                h[n] = fmaf(__expf(dl * a[n]), h[n], dp[16 + n] * u);
        }
        size_t sbase = (size_t)bid * 16 * D_INNER + t;
        #pragma unroll
        for (int n = 0; n < 16; n++) Ssum[sbase + (size_t)n * D_INNER] = h[n];
        sdsum[(size_t)bid * D_INNER + t] = sd;
    }
}

// ---------------------------------------------------------------------------
// k_comb: two-level exclusive prefix over 512 chunk summaries. Grid 512x512.
// ---------------------------------------------------------------------------
__global__ __launch_bounds__(512, 4) void k_comb(
    const float* __restrict__ alogL, const float* __restrict__ sdsum,
    float* __restrict__ Ssum)
{
    const int t = threadIdx.x, bid = blockIdx.x;
    __shared__ float S_l[32][17], sd_l[32][17];
    int ch32 = t & 31, seg = t >> 5;
    int chain = bid * 32 + ch32;
    int d = chain & 511;
    int n = (chain >> 9) & 15;
    int b = chain >> 13;
    float a = -__expf(alogL[(size_t)d * 16 + n]);
    int c0 = b * CPB + seg * 16;

    float s_r[16], sd_r[16];
    float S = 0.f, sdt = 0.f;
    #pragma unroll
    for (int j = 0; j < 16; j++) {
        size_t c = (size_t)(c0 + j);
        float s  = Ssum[(c * 16 + n) * D_INNER + d];
        float sd = sdsum[c * D_INNER + d];
        s_r[j] = s; sd_r[j] = sd;
        S = fmaf(__expf(a * sd), S, s);
        sdt += sd;
    }
    S_l[ch32][seg] = S;
    sd_l[ch32][seg] = sdt;
    __syncthreads();

    if (t < 32) {
        float hi = 0.f;
        #pragma unroll
        for (int g = 0; g < 16; g++) {
            float Sv = S_l[t][g], sdv = sd_l[t][g];
            S_l[t][g] = hi;
            hi = fmaf(__expf(a * sdv), hi, Sv);
        }
    }
    __syncthreads();

    float hi = S_l[ch32][seg];
    #pragma unroll
    for (int j = 0; j < 16; j++) {
        size_t c = (size_t)(c0 + j);
        Ssum[(c * 16 + n) * D_INNER + d] = hi;
        hi = fmaf(__expf(a * sd_r[j]), hi, s_r[j]);
    }
}

// ---------------------------------------------------------------------------
// k_back: 8-row chunk. dbl staged to LDS; rescan from true h_init + D-skip +
// SiLU(z) gate; out_proj MFMA (tiled weights, hoisted af) + residual.
// Grid 512 x 512.
// ---------------------------------------------------------------------------
__global__ __launch_bounds__(512, 3) void k_back(
    const float* __restrict__ dbl, const ushort* __restrict__ xcB,
    const ushort* __restrict__ zsB, const float* __restrict__ Ssum,
    const float* __restrict__ dpwL, const float* __restrict__ dpbL,
    const float* __restrict__ alogL, const float* __restrict__ dparL,
    const ushort* __restrict__ opwT, const float* __restrict__ xin,
    float* __restrict__ xout)
{
    const int t = threadIdx.x, bid = blockIdx.x;
    const int lane = t & 63, w = t >> 6, l15 = lane & 15, quad = lane >> 4;
    __shared__ ushort yy_s[16 * XC_STR];   // 16.6 KB (rows 8-15 garbage)
    __shared__ float  dbl_l[8 * 48];       //  1.5 KB
    int m0 = bid * LCH;

    // ---- stage this chunk's dbl rows (block-uniform data) into LDS ----
    if (t < 8 * 48) dbl_l[t] = dbl[(size_t)m0 * 48 + t];
    __syncthreads();

    // ---- rescan, d = t ----
    {
        float a[16], wdp[16];
        #pragma unroll
        for (int n = 0; n < 16; n++) a[n] = -__expf(alogL[(size_t)t * 16 + n]);
        *(float4*)&wdp[0]  = *(const float4*)(dpwL + (size_t)t * 16 + 0);
        *(float4*)&wdp[4]  = *(const float4*)(dpwL + (size_t)t * 16 + 4);
        *(float4*)&wdp[8]  = *(const float4*)(dpwL + (size_t)t * 16 + 8);
        *(float4*)&wdp[12] = *(const float4*)(dpwL + (size_t)t * 16 + 12);
        float bias = dpbL[t];
        float Dd = dparL[t];
        float h[16];
        size_t sbase = (size_t)bid * 16 * D_INNER + t;
        #pragma unroll
        for (int n = 0; n < 16; n++) h[n] = Ssum[sbase + (size_t)n * D_INNER];
        for (int j = 0; j < LCH; j++) {
            int row = m0 + j;
            const float* dp = &dbl_l[j * 48];
            float d0 = 0.f, d1 = 0.f;
            #pragma unroll
            for (int r2 = 0; r2 < 8; r2++) {
                d0 = fmaf(dp[r2], wdp[r2], d0);
                d1 = fmaf(dp[8 + r2], wdp[8 + r2], d1);
            }
            float dl = softplus_f(bias + d0 + d1);
            float xv = bf2f(xcB[(size_t)row * D_INNER + t]);
            float gate = bf2f(zsB[(size_t)row * D_INNER + t]);
            float u = dl * xv;
            float y0 = 0.f, y1 = 0.f, y2 = 0.f, y3 = 0.f;
            #pragma unroll
            for (int q = 0; q < 4; q++) {
                h[4 * q + 0] = fmaf(__expf(dl * a[4 * q + 0]), h[4 * q + 0], dp[16 + 4 * q + 0] * u);
                h[4 * q + 1] = fmaf(__expf(dl * a[4 * q + 1]), h[4 * q + 1], dp[16 + 4 * q + 1] * u);
                h[4 * q + 2] = fmaf(__expf(dl * a[4 * q + 2]), h[4 * q + 2], dp[16 + 4 * q + 2] * u);
                h[4 * q + 3] = fmaf(__expf(dl * a[4 * q + 3]), h[4 * q + 3], dp[16 + 4 * q + 3] * u);
                y0 = fmaf(h[4 * q + 0], dp[32 + 4 * q + 0], y0);
                y1 = fmaf(h[4 * q + 1], dp[32 + 4 * q + 1], y1);
                y2 = fmaf(h[4 * q + 2], dp[32 + 4 * q + 2], y2);
                y3 = fmaf(h[4 * q + 3], dp[32 + 4 * q + 3], y3);
            }
            float y = (y0 + y1) + (y2 + y3) + xv * Dd;
            yy_s[j * XC_STR + t] = f2bf(y * gate);
        }
    }
    __syncthreads();

    // ---- out_proj MFMA + residual: hoisted af[16], dual acc, tiled opwT ---
    {
        bf16x8 af[16];
        #pragma unroll
        for (int k8 = 0; k8 < 16; k8++)
            af[k8] = *(const bf16x8*)&yy_s[l15 * XC_STR + quad * 8 + k8 * 32];
        f32x4 acc0 = (f32x4){0.f, 0.f, 0.f, 0.f};
        f32x4 acc1 = (f32x4){0.f, 0.f, 0.f, 0.f};
        const ushort* wb = opwT + (size_t)w * 2 * 16 * 512 + l15 * 32 + quad * 8;
        #pragma unroll
        for (int k8 = 0; k8 < 16; k8++) {
            bf16x8 b0 = *(const bf16x8*)(wb + k8 * 512);
            bf16x8 b1 = *(const bf16x8*)(wb + (16 + k8) * 512);
            acc0 = __builtin_amdgcn_mfma_f32_16x16x32_bf16(af[k8], b0, acc0, 0, 0, 0);
            acc1 = __builtin_amdgcn_mfma_f32_16x16x32_bf16(af[k8], b1, acc1, 0, 0, 0);
        }
        #pragma unroll
        for (int f = 0; f < 2; f++) {
            int n = w * 32 + f * 16 + l15;
            const f32x4& acc = (f == 0) ? acc0 : acc1;
            #pragma unroll
            for (int r2 = 0; r2 < 4; r2++) {
                int rl = quad * 4 + r2;
                if (rl < LCH) {
                    int row = m0 + rl;
                    xout[(size_t)row * D_MODEL + n] =
                        acc[r2] + xin[(size_t)row * D_MODEL + n];
                }
            }
        }
    }
}

// ---------------------------------------------------------------------------
// Launch. Inter-layer activation routed through d_out.
// ---------------------------------------------------------------------------
extern "C" void kernel_launch(void* const* d_in, const int* in_sizes, int n_in,
                              void* d_out, int out_size, void* d_ws, size_t ws_size,
                              hipStream_t stream)
{
    const float* x    = (const float*)d_in[0];
    const float* lnw  = (const float*)d_in[1];
    const float* lnb  = (const float*)d_in[2];
    const float* ipw  = (const float*)d_in[3];
    const float* cw   = (const float*)d_in[4];
    const float* cb   = (const float*)d_in[5];
    const float* xpw  = (const float*)d_in[6];
    const float* dpw  = (const float*)d_in[7];
    const float* dpb  = (const float*)d_in[8];
    const float* alog = (const float*)d_in[9];
    const float* dpar = (const float*)d_in[10];
    const float* opw  = (const float*)d_in[11];
    float* out = (float*)d_out;

    char* p = (char*)d_ws;
    auto alloc = [&](size_t bytes) { char* r = p; p += (bytes + 255) & ~(size_t)255; return r; };
    ushort* zsB   = (ushort*)alloc((size_t)MROWS * D_INNER * 2);
    ushort* xcB   = (ushort*)alloc((size_t)MROWS * D_INNER * 2);
    float*  dbl   = (float*)alloc((size_t)MROWS * 48 * 4);
    float*  Ssum  = (float*)alloc((size_t)NCH * 16 * D_INNER * 4);
    float*  sdsum = (float*)alloc((size_t)NCH * D_INNER * 4);
    ushort* ipwT  = (ushort*)alloc((size_t)DEPTH * 262144 * 2);
    ushort* xpwT  = (ushort*)alloc((size_t)DEPTH * 24576 * 2);
    ushort* opwT  = (ushort*)alloc((size_t)DEPTH * 131072 * 2);

    k_cvt<<<512, 256, 0, stream>>>(ipw, xpw, opw, ipwT, xpwT, opwT);

    for (int lyr = 0; lyr < DEPTH; lyr++) {
        const float* xin = (lyr == 0) ? x : out;
        float* xout = out;
        const float* alogL = alog + (size_t)lyr * D_INNER * D_STATE;
        const float* dpwL  = dpw + (size_t)lyr * D_INNER * DT_RANK;
        const float* dpbL  = dpb + lyr * D_INNER;

        k_front<<<NCH, 512, 0, stream>>>(
            xin, lnw + lyr * D_MODEL, lnb + lyr * D_MODEL,
            ipwT + (size_t)lyr * 262144,
            cw + (size_t)lyr * D_INNER * D_CONV, cb + lyr * D_INNER,
            xpwT + (size_t)lyr * 24576, dpwL, dpbL, alogL,
            zsB, xcB, dbl, Ssum, sdsum);

        k_comb<<<512, 512, 0, stream>>>(alogL, sdsum, Ssum);

        k_back<<<NCH, 512, 0, stream>>>(
            dbl, xcB, zsB, Ssum, dpwL, dpbL, alogL,
            dpar + lyr * D_INNER,
            opwT + (size_t)lyr * 131072, xin, xout);
    }
}